// Round 1
// baseline (186.004 us; speedup 1.0000x reference)
//
#include <hip/hip_runtime.h>

#define DEV __device__ __forceinline__

typedef __attribute__((ext_vector_type(4))) float f32x4;
typedef __attribute__((ext_vector_type(4))) unsigned short us4;
typedef __bf16 bf16_t;
typedef __attribute__((ext_vector_type(8))) bf16_t bf16x8;

// B=8, S=2048, D_MODEL=256, H=4, DEPTH=64, BH=32, M=B*S=16384

DEV unsigned short f2bf(float f) {
  union { float f; unsigned u; } x; x.f = f;
  return (unsigned short)((x.u + 0x7fffu + ((x.u >> 16) & 1u)) >> 16);
}

DEV void gl2lds16(const void* g, void* l) {
  __builtin_amdgcn_global_load_lds(
      (const __attribute__((address_space(1))) unsigned int*)g,
      (__attribute__((address_space(3))) unsigned int*)l, 16, 0, 0);
}

DEV f32x4 mfma16(bf16x8 a, bf16x8 b, f32x4 c) {
  return __builtin_amdgcn_mfma_f32_16x16x32_bf16(a, b, c, 0, 0, 0);
}

// ---- transpose+convert the 4 weight matrices: WT[m][n][k] = W[k][n] (bf16) ----
__global__ __launch_bounds__(256) void prep_w(
    const float* __restrict__ wq, const float* __restrict__ wk,
    const float* __restrict__ wv, const float* __restrict__ wo,
    unsigned short* __restrict__ wt) {
  int t = blockIdx.x * 256 + threadIdx.x;   // 0 .. 262143
  int m = t >> 16;
  int i = t & 65535;
  int n = i >> 8, k = i & 255;
  const float* W = (m == 0) ? wq : (m == 1) ? wk : (m == 2) ? wv : wo;
  wt[m * 65536 + n * 256 + k] = f2bf(W[k * 256 + n]);
}

// ---- QKV projection GEMM: C[16384,256] = A(f32) * W + b, head-split outputs ----
__global__ __launch_bounds__(256) void gemm_qkv(
    const float* __restrict__ Aq, const float* __restrict__ Ak, const float* __restrict__ Av,
    const float* __restrict__ bq, const float* __restrict__ bk, const float* __restrict__ bv,
    const unsigned short* __restrict__ wt,
    unsigned short* __restrict__ Qh, unsigned short* __restrict__ Kh,
    unsigned short* __restrict__ VhT) {
  __shared__ __align__(16) unsigned short At[128 * 32];
  __shared__ __align__(16) unsigned short Bt[128 * 32];
  const int p = blockIdx.z;
  const float* A    = (p == 0) ? Aq : (p == 1) ? Ak : Av;
  const float* bias = (p == 0) ? bq : (p == 1) ? bk : bv;
  const unsigned short* WT = wt + p * 65536;
  const int m0 = blockIdx.x * 128, n0 = blockIdx.y * 128;
  const int t = threadIdx.x, lane = t & 63;
  const int wid = t >> 6, wm = wid >> 1, wn = wid & 1;
  const int lr = lane & 15, lg = lane >> 4;

  f32x4 acc[4][4] = {};

  for (int k0 = 0; k0 < 256; k0 += 32) {
    // stage A tile [128][32] f32 -> bf16 via registers
#pragma unroll
    for (int i = 0; i < 4; ++i) {
      int u = t + i * 256;          // 1024 float4 units
      int row = u >> 3, c4 = u & 7;
      f32x4 x = *(const f32x4*)(A + (m0 + row) * 256 + k0 + c4 * 4);
      us4 pk;
      pk[0] = f2bf(x[0]); pk[1] = f2bf(x[1]);
      pk[2] = f2bf(x[2]); pk[3] = f2bf(x[3]);
      *(us4*)(&At[row * 32 + c4 * 4]) = pk;
    }
    // stage B tile [128 n][32 k] bf16 direct to LDS
#pragma unroll
    for (int i = 0; i < 2; ++i) {
      int u = t + i * 256;          // 512 16B units, wave-linear
      int row = u >> 2, c16 = u & 3;
      gl2lds16(WT + (n0 + row) * 256 + k0 + c16 * 8, &Bt[row * 32 + c16 * 8]);
    }
    __syncthreads();
    bf16x8 af[4], bfr[4];
#pragma unroll
    for (int m = 0; m < 4; ++m)
      af[m] = *(const bf16x8*)(&At[(wm * 64 + m * 16 + lr) * 32 + lg * 8]);
#pragma unroll
    for (int n = 0; n < 4; ++n)
      bfr[n] = *(const bf16x8*)(&Bt[(wn * 64 + n * 16 + lr) * 32 + lg * 8]);
#pragma unroll
    for (int m = 0; m < 4; ++m)
#pragma unroll
      for (int n = 0; n < 4; ++n)
        acc[m][n] = mfma16(af[m], bfr[n], acc[m][n]);
    __syncthreads();
  }

#pragma unroll
  for (int n = 0; n < 4; ++n) {
    int col = n0 + wn * 64 + n * 16 + lr;
    float bb = bias[col];
    int h = col >> 6, d = col & 63;
#pragma unroll
    for (int m = 0; m < 4; ++m) {
      int rowb = m0 + wm * 64 + m * 16 + lg * 4;
#pragma unroll
      for (int r = 0; r < 4; ++r) {
        int srow = rowb + r;
        int b = srow >> 11, s = srow & 2047;
        int bh = b * 4 + h;
        unsigned short val = f2bf(acc[m][n][r] + bb);
        if (p == 0)      Qh[(bh * 2048 + s) * 64 + d] = val;
        else if (p == 1) Kh[(bh * 2048 + s) * 64 + d] = val;
        else             VhT[((bh * 64 + d) * 2048) + s] = val;
      }
    }
  }
}

// ---- fused flash attention: per (q-block 64, bh); 4 waves x 16 q-rows ----
__global__ __launch_bounds__(256) void attn(
    const unsigned short* __restrict__ Qh, const unsigned short* __restrict__ Kh,
    const unsigned short* __restrict__ VhT, const float* __restrict__ mask,
    unsigned short* __restrict__ Aout) {
  __shared__ __align__(16) unsigned short Kt[64 * 64];
  __shared__ __align__(16) unsigned short Vt[64 * 64];   // transposed: [d][key]
  __shared__ __align__(16) unsigned short Pt[4][16 * 64];
  const int bh = blockIdx.y;
  const int q0 = blockIdx.x * 64;
  const int t = threadIdx.x, lane = t & 63, wid = t >> 6;
  const int lr = lane & 15, lg = lane >> 4;
  const int qrow = q0 + wid * 16;
  const float* mrow = mask + (bh >> 2) * 2048;

  bf16x8 qf[2];
#pragma unroll
  for (int ds = 0; ds < 2; ++ds)
    qf[ds] = *(const bf16x8*)(Qh + (bh * 2048 + qrow + lr) * 64 + ds * 32 + lg * 8);

  f32x4 accO[4] = {};
  float mrun[4], lrun[4];
#pragma unroll
  for (int r = 0; r < 4; ++r) { mrun[r] = -3.0e38f; lrun[r] = 0.f; }

  for (int kv0 = 0; kv0 < 2048; kv0 += 64) {
    // stage K [64 key][64 d] and VT [64 d][64 key], bf16, 8KB each
#pragma unroll
    for (int i = 0; i < 2; ++i) {
      int u = t + i * 256;          // 512 16B units each
      int row = u >> 3, c16 = u & 7;
      gl2lds16(Kh + (bh * 2048 + kv0 + row) * 64 + c16 * 8, &Kt[row * 64 + c16 * 8]);
      gl2lds16(VhT + (bh * 64 + row) * 2048 + kv0 + c16 * 8, &Vt[row * 64 + c16 * 8]);
    }
    __syncthreads();

    // S = Q K^T
    f32x4 accS[4] = {};
#pragma unroll
    for (int kb = 0; kb < 4; ++kb)
#pragma unroll
      for (int ds = 0; ds < 2; ++ds) {
        bf16x8 kf = *(const bf16x8*)(&Kt[(kb * 16 + lr) * 64 + ds * 32 + lg * 8]);
        accS[kb] = mfma16(qf[ds], kf, accS[kb]);
      }

    // logits: *scale + mask*(-1e9)  (f32)
    float sv[4][4];
#pragma unroll
    for (int kb = 0; kb < 4; ++kb) {
      float mk = mrow[kv0 + kb * 16 + lr] * -1e9f;
#pragma unroll
      for (int r = 0; r < 4; ++r)
        sv[kb][r] = accS[kb][r] * 0.125f + mk;
    }
    // online softmax (rows live on lanes with same lg; reduce over low 4 lane bits)
    float mnew[4];
#pragma unroll
    for (int r = 0; r < 4; ++r) {
      float mx = fmaxf(fmaxf(sv[0][r], sv[1][r]), fmaxf(sv[2][r], sv[3][r]));
#pragma unroll
      for (int off = 1; off < 16; off <<= 1)
        mx = fmaxf(mx, __shfl_xor(mx, off));
      mnew[r] = fmaxf(mrun[r], mx);
      float al = __expf(mrun[r] - mnew[r]);
      lrun[r] *= al;
#pragma unroll
      for (int db = 0; db < 4; ++db) accO[db][r] *= al;
      mrun[r] = mnew[r];
    }
#pragma unroll
    for (int kb = 0; kb < 4; ++kb)
#pragma unroll
      for (int r = 0; r < 4; ++r)
        sv[kb][r] = __expf(sv[kb][r] - mnew[r]);
#pragma unroll
    for (int r = 0; r < 4; ++r) {
      float s = sv[0][r] + sv[1][r] + sv[2][r] + sv[3][r];
#pragma unroll
      for (int off = 1; off < 16; off <<= 1)
        s += __shfl_xor(s, off);
      lrun[r] += s;
    }
    // P -> per-wave LDS (re-fragment for PV A-operand)
#pragma unroll
    for (int kb = 0; kb < 4; ++kb)
#pragma unroll
      for (int r = 0; r < 4; ++r)
        Pt[wid][(lg * 4 + r) * 64 + kb * 16 + lr] = f2bf(sv[kb][r]);
    // O += P V
#pragma unroll
    for (int ks = 0; ks < 2; ++ks) {
      bf16x8 pf = *(const bf16x8*)(&Pt[wid][lr * 64 + ks * 32 + lg * 8]);
#pragma unroll
      for (int db = 0; db < 4; ++db) {
        bf16x8 vf = *(const bf16x8*)(&Vt[(db * 16 + lr) * 64 + ks * 32 + lg * 8]);
        accO[db] = mfma16(pf, vf, accO[db]);
      }
    }
    __syncthreads();
  }

  const int b = bh >> 2, h = bh & 3;
#pragma unroll
  for (int db = 0; db < 4; ++db)
#pragma unroll
    for (int r = 0; r < 4; ++r) {
      int srow = qrow + lg * 4 + r;
      float o = accO[db][r] / lrun[r];
      Aout[(b * 2048 + srow) * 256 + h * 64 + db * 16 + lr] = f2bf(o);
    }
}

// ---- output projection: out[16384,256] = Aout(bf16) * Wo + bo (f32 out) ----
__global__ __launch_bounds__(256) void gemm_out(
    const unsigned short* __restrict__ Aout, const unsigned short* __restrict__ wt,
    const float* __restrict__ bo, float* __restrict__ out) {
  __shared__ __align__(16) unsigned short At[128 * 32];
  __shared__ __align__(16) unsigned short Bt[128 * 32];
  const unsigned short* WT = wt + 3 * 65536;
  const int m0 = blockIdx.x * 128, n0 = blockIdx.y * 128;
  const int t = threadIdx.x, lane = t & 63;
  const int wid = t >> 6, wm = wid >> 1, wn = wid & 1;
  const int lr = lane & 15, lg = lane >> 4;

  f32x4 acc[4][4] = {};

  for (int k0 = 0; k0 < 256; k0 += 32) {
#pragma unroll
    for (int i = 0; i < 2; ++i) {
      int u = t + i * 256;
      int row = u >> 2, c16 = u & 3;
      gl2lds16(Aout + (m0 + row) * 256 + k0 + c16 * 8, &At[row * 32 + c16 * 8]);
      gl2lds16(WT + (n0 + row) * 256 + k0 + c16 * 8, &Bt[row * 32 + c16 * 8]);
    }
    __syncthreads();
    bf16x8 af[4], bfr[4];
#pragma unroll
    for (int m = 0; m < 4; ++m)
      af[m] = *(const bf16x8*)(&At[(wm * 64 + m * 16 + lr) * 32 + lg * 8]);
#pragma unroll
    for (int n = 0; n < 4; ++n)
      bfr[n] = *(const bf16x8*)(&Bt[(wn * 64 + n * 16 + lr) * 32 + lg * 8]);
#pragma unroll
    for (int m = 0; m < 4; ++m)
#pragma unroll
      for (int n = 0; n < 4; ++n)
        acc[m][n] = mfma16(af[m], bfr[n], acc[m][n]);
    __syncthreads();
  }

#pragma unroll
  for (int n = 0; n < 4; ++n) {
    int col = n0 + wn * 64 + n * 16 + lr;
    float bb = bo[col];
#pragma unroll
    for (int m = 0; m < 4; ++m) {
      int rowb = m0 + wm * 64 + m * 16 + lg * 4;
#pragma unroll
      for (int r = 0; r < 4; ++r)
        out[(rowb + r) * 256 + col] = acc[m][n][r] + bb;
    }
  }
}

extern "C" void kernel_launch(void* const* d_in, const int* in_sizes, int n_in,
                              void* d_out, int out_size, void* d_ws, size_t ws_size,
                              hipStream_t stream) {
  const float* v    = (const float*)d_in[0];
  const float* k    = (const float*)d_in[1];
  const float* q    = (const float*)d_in[2];
  const float* mask = (const float*)d_in[3];
  const float* wq   = (const float*)d_in[4];
  const float* bq   = (const float*)d_in[5];
  const float* wk   = (const float*)d_in[6];
  const float* bk   = (const float*)d_in[7];
  const float* wv   = (const float*)d_in[8];
  const float* bv   = (const float*)d_in[9];
  const float* wo   = (const float*)d_in[10];
  const float* bo   = (const float*)d_in[11];
  float* out = (float*)d_out;
  char* ws = (char*)d_ws;

  // ws layout (bytes): wt 524288 | Qh 8388608 | Kh 8388608 | VhT 8388608 | Aout 8388608
  unsigned short* wt  = (unsigned short*)(ws);
  unsigned short* Qh  = (unsigned short*)(ws + 524288);
  unsigned short* Kh  = (unsigned short*)(ws + 524288 + 8388608);
  unsigned short* VhT = (unsigned short*)(ws + 524288 + 2 * 8388608);
  unsigned short* Ao  = (unsigned short*)(ws + 524288 + 3 * 8388608);

  prep_w<<<dim3(1024), dim3(256), 0, stream>>>(wq, wk, wv, wo, wt);
  gemm_qkv<<<dim3(128, 2, 3), dim3(256), 0, stream>>>(q, k, v, bq, bk, bv, wt, Qh, Kh, VhT);
  attn<<<dim3(32, 32), dim3(256), 0, stream>>>(Qh, Kh, VhT, mask, Ao);
  gemm_out<<<dim3(128, 2), dim3(256), 0, stream>>>(Ao, wt, bo, out);
}

// Round 2
// 154.023 us; speedup vs baseline: 1.2076x; 1.2076x over previous
//
#include <hip/hip_runtime.h>

#define DEV __device__ __forceinline__

typedef __attribute__((ext_vector_type(4))) float f32x4;
typedef __bf16 bf16_t;
typedef __attribute__((ext_vector_type(8))) bf16_t bf16x8;
typedef __attribute__((ext_vector_type(8))) unsigned short us8;

// B=8, S=2048, D_MODEL=256, H=4, DEPTH=64, BH=32, M=B*S=16384

DEV unsigned short f2bf(float f) {
  bf16_t h = (bf16_t)f;                 // v_cvt_pk_bf16_f32 (RNE)
  return __builtin_bit_cast(unsigned short, h);
}

DEV void gl2lds16(const void* g, void* l) {
  __builtin_amdgcn_global_load_lds(
      (const __attribute__((address_space(1))) unsigned int*)g,
      (__attribute__((address_space(3))) unsigned int*)l, 16, 0, 0);
}

DEV f32x4 mfma16(bf16x8 a, bf16x8 b, f32x4 c) {
  return __builtin_amdgcn_mfma_f32_16x16x32_bf16(a, b, c, 0, 0, 0);
}

// ---- weights: WT[m][n][k] = W[k][n] (bf16); mask prescale ----
__global__ __launch_bounds__(256) void prep_w(
    const float* __restrict__ wq, const float* __restrict__ wk,
    const float* __restrict__ wv, const float* __restrict__ wo,
    const float* __restrict__ mask,
    unsigned short* __restrict__ wt, float* __restrict__ mprep) {
  int t = blockIdx.x * 256 + threadIdx.x;   // 0 .. 262143
  if (t < 16384) mprep[t] = mask[t] * -1.442695041e9f;   // *(-1e9)*log2(e)
  int m = t >> 16;
  int i = t & 65535;
  int n = i >> 8, k = i & 255;
  const float* W = (m == 0) ? wq : (m == 1) ? wk : (m == 2) ? wv : wo;
  wt[m * 65536 + n * 256 + k] = f2bf(W[k * 256 + n]);
}

// ---- QKV projection GEMM: [128 rows][64 k] swizzled tiles, BK=64 ----
__global__ __launch_bounds__(256) void gemm_qkv(
    const float* __restrict__ Aq, const float* __restrict__ Ak, const float* __restrict__ Av,
    const float* __restrict__ bq, const float* __restrict__ bk, const float* __restrict__ bv,
    const unsigned short* __restrict__ wt,
    unsigned short* __restrict__ Qh, unsigned short* __restrict__ Kh,
    unsigned short* __restrict__ VhT) {
  __shared__ __align__(16) unsigned short At[128 * 64];
  __shared__ __align__(16) unsigned short Bt[128 * 64];
  const int p = blockIdx.z;
  const float* A    = (p == 0) ? Aq : (p == 1) ? Ak : Av;
  const float* bias = (p == 0) ? bq : (p == 1) ? bk : bv;
  const unsigned short* WT = wt + p * 65536;
  const int m0 = blockIdx.x * 128, n0 = blockIdx.y * 128;
  const int t = threadIdx.x, lane = t & 63;
  const int wid = t >> 6, wm = wid >> 1, wn = wid & 1;
  const int lr = lane & 15, lg = lane >> 4;

  f32x4 acc[4][4] = {};

  for (int k0 = 0; k0 < 256; k0 += 64) {
    // A: f32 -> bf16, reg-staged, swizzled write (1024 16B units)
#pragma unroll
    for (int i = 0; i < 4; ++i) {
      int u = t + i * 256;
      int row = u >> 3, un = u & 7;
      const float* src = A + (m0 + row) * 256 + k0 + un * 8;
      f32x4 x0 = *(const f32x4*)src;
      f32x4 x1 = *(const f32x4*)(src + 4);
      us8 pk;
      pk[0] = f2bf(x0[0]); pk[1] = f2bf(x0[1]); pk[2] = f2bf(x0[2]); pk[3] = f2bf(x0[3]);
      pk[4] = f2bf(x1[0]); pk[5] = f2bf(x1[1]); pk[6] = f2bf(x1[2]); pk[7] = f2bf(x1[3]);
      *(us8*)(&At[row * 64 + (un ^ (row & 7)) * 8]) = pk;
    }
    // B: direct to LDS, pre-swizzled global source
#pragma unroll
    for (int i = 0; i < 4; ++i) {
      int u = t + i * 256;
      int row = u >> 3, g = (u & 7) ^ (row & 7);
      gl2lds16(WT + (n0 + row) * 256 + k0 + g * 8, &Bt[u * 8]);
    }
    __syncthreads();
#pragma unroll
    for (int ds = 0; ds < 2; ++ds) {
      bf16x8 af[4], bfr[4];
#pragma unroll
      for (int m = 0; m < 4; ++m)
        af[m] = *(const bf16x8*)(&At[(wm * 64 + m * 16 + lr) * 64 + (((ds << 2) | lg) ^ (lr & 7)) * 8]);
#pragma unroll
      for (int n = 0; n < 4; ++n)
        bfr[n] = *(const bf16x8*)(&Bt[(wn * 64 + n * 16 + lr) * 64 + (((ds << 2) | lg) ^ (lr & 7)) * 8]);
#pragma unroll
      for (int m = 0; m < 4; ++m)
#pragma unroll
        for (int n = 0; n < 4; ++n)
          acc[m][n] = mfma16(af[m], bfr[n], acc[m][n]);
    }
    __syncthreads();
  }

#pragma unroll
  for (int n = 0; n < 4; ++n) {
    int col = n0 + wn * 64 + n * 16 + lr;
    float bb = bias[col];
    int h = col >> 6, d = col & 63;
#pragma unroll
    for (int m = 0; m < 4; ++m) {
      int rowb = m0 + wm * 64 + m * 16 + lg * 4;
#pragma unroll
      for (int r = 0; r < 4; ++r) {
        int srow = rowb + r;
        int b = srow >> 11, s = srow & 2047;
        int bh = b * 4 + h;
        unsigned short val = f2bf(acc[m][n][r] + bb);
        if (p == 0)      Qh[(bh * 2048 + s) * 64 + d] = val;
        else if (p == 1) Kh[(bh * 2048 + s) * 64 + d] = val;
        else             VhT[((bh * 64 + d) * 2048) + s] = val;
      }
    }
  }
}

// ---- fused flash attention: dbuf K/V prefetch, swizzled LDS, exp2 softmax ----
__global__ __launch_bounds__(256) void attn(
    const unsigned short* __restrict__ Qh, const unsigned short* __restrict__ Kh,
    const unsigned short* __restrict__ VhT, const float* __restrict__ mprep,
    unsigned short* __restrict__ Aout) {
  __shared__ __align__(16) unsigned short Kt[2][4096];
  __shared__ __align__(16) unsigned short Vt[2][4096];
  __shared__ __align__(16) unsigned short Pt[4][1024];
  const int bh = blockIdx.y;
  const int q0 = blockIdx.x * 64;
  const int t = threadIdx.x, lane = t & 63, wid = t >> 6;
  const int lr = lane & 15, lg = lane >> 4;
  const int qrow = q0 + wid * 16;
  const unsigned short* Kbase = Kh + bh * 131072;
  const unsigned short* Vbase = VhT + bh * 131072;
  const float* mrow = mprep + (bh >> 2) * 2048;

  bf16x8 qf[2];
#pragma unroll
  for (int ds = 0; ds < 2; ++ds)
    qf[ds] = *(const bf16x8*)(Qh + (bh * 2048 + qrow + lr) * 64 + ds * 32 + lg * 8);

  f32x4 accO[4] = {};
  float mrun[4], lrun[4];
#pragma unroll
  for (int r = 0; r < 4; ++r) { mrun[r] = -3.0e38f; lrun[r] = 0.f; }

#define STAGE(buf, kv)                                                        \
  {                                                                           \
    _Pragma("unroll")                                                         \
    for (int i = 0; i < 2; ++i) {                                             \
      int u = t + i * 256;                                                    \
      int row = u >> 3, g = (u & 7) ^ (row & 7);                              \
      gl2lds16(Kbase + ((kv) + row) * 64 + g * 8, &Kt[buf][u * 8]);           \
      gl2lds16(Vbase + row * 2048 + (kv) + g * 8, &Vt[buf][u * 8]);           \
    }                                                                         \
  }

  STAGE(0, 0)
  __syncthreads();
  int cur = 0;

  for (int kv0 = 0; kv0 < 2048; kv0 += 64) {
    if (kv0 + 64 < 2048) STAGE(cur ^ 1, kv0 + 64)

    // S = Q K^T
    f32x4 accS[4] = {};
#pragma unroll
    for (int kb = 0; kb < 4; ++kb)
#pragma unroll
      for (int ds = 0; ds < 2; ++ds) {
        bf16x8 kf = *(const bf16x8*)(&Kt[cur][(kb * 16 + lr) * 64 + (((ds << 2) | lg) ^ (lr & 7)) * 8]);
        accS[kb] = mfma16(qf[ds], kf, accS[kb]);
      }

    // logits in log2 domain: S*(0.125*log2e) + mask*(-1e9*log2e)
    float sv[4][4];
#pragma unroll
    for (int kb = 0; kb < 4; ++kb) {
      float mk = mrow[kv0 + kb * 16 + lr];
#pragma unroll
      for (int r = 0; r < 4; ++r)
        sv[kb][r] = accS[kb][r] * 0.1803368801f + mk;
    }
    float mnew[4];
#pragma unroll
    for (int r = 0; r < 4; ++r) {
      float mx = fmaxf(fmaxf(sv[0][r], sv[1][r]), fmaxf(sv[2][r], sv[3][r]));
#pragma unroll
      for (int off = 1; off < 16; off <<= 1)
        mx = fmaxf(mx, __shfl_xor(mx, off));
      mnew[r] = fmaxf(mrun[r], mx);
      float al = __builtin_amdgcn_exp2f(mrun[r] - mnew[r]);
      lrun[r] *= al;
#pragma unroll
      for (int db = 0; db < 4; ++db) accO[db][r] *= al;
      mrun[r] = mnew[r];
    }
#pragma unroll
    for (int kb = 0; kb < 4; ++kb)
#pragma unroll
      for (int r = 0; r < 4; ++r)
        sv[kb][r] = __builtin_amdgcn_exp2f(sv[kb][r] - mnew[r]);
#pragma unroll
    for (int r = 0; r < 4; ++r) {
      float s = (sv[0][r] + sv[1][r]) + (sv[2][r] + sv[3][r]);
#pragma unroll
      for (int off = 1; off < 16; off <<= 1)
        s += __shfl_xor(s, off);
      lrun[r] += s;
    }
    // P -> per-wave LDS (swizzled write + read; same-wave dep, no barrier)
#pragma unroll
    for (int kb = 0; kb < 4; ++kb)
#pragma unroll
      for (int r = 0; r < 4; ++r) {
        int col = kb * 16 + lr, prow = lg * 4 + r;
        Pt[wid][prow * 64 + (((col >> 3) ^ (prow & 7)) << 3) + (lr & 7)] = f2bf(sv[kb][r]);
      }
    // O += P V
#pragma unroll
    for (int ks = 0; ks < 2; ++ks) {
      bf16x8 pf = *(const bf16x8*)(&Pt[wid][lr * 64 + (((ks << 2) | lg) ^ (lr & 7)) * 8]);
#pragma unroll
      for (int db = 0; db < 4; ++db) {
        bf16x8 vf = *(const bf16x8*)(&Vt[cur][(db * 16 + lr) * 64 + (((ks << 2) | lg) ^ (lr & 7)) * 8]);
        accO[db] = mfma16(pf, vf, accO[db]);
      }
    }
    __syncthreads();   // drains this iter's prefetch (vmcnt) + releases cur buf
    cur ^= 1;
  }
#undef STAGE

  const int b = bh >> 2, h = bh & 3;
  float inv[4];
#pragma unroll
  for (int r = 0; r < 4; ++r) inv[r] = __builtin_amdgcn_rcpf(lrun[r]);
#pragma unroll
  for (int db = 0; db < 4; ++db)
#pragma unroll
    for (int r = 0; r < 4; ++r) {
      int srow = qrow + lg * 4 + r;
      Aout[(b * 2048 + srow) * 256 + h * 64 + db * 16 + lr] = f2bf(accO[db][r] * inv[r]);
    }
}

// ---- output projection: out = Aout(bf16) * Wo + bo (f32 out) ----
__global__ __launch_bounds__(256) void gemm_out(
    const unsigned short* __restrict__ Aout, const unsigned short* __restrict__ wt,
    const float* __restrict__ bo, float* __restrict__ out) {
  __shared__ __align__(16) unsigned short At[128 * 64];
  __shared__ __align__(16) unsigned short Bt[128 * 64];
  const unsigned short* WT = wt + 3 * 65536;
  const int m0 = blockIdx.x * 128, n0 = blockIdx.y * 128;
  const int t = threadIdx.x, lane = t & 63;
  const int wid = t >> 6, wm = wid >> 1, wn = wid & 1;
  const int lr = lane & 15, lg = lane >> 4;

  f32x4 acc[4][4] = {};

  for (int k0 = 0; k0 < 256; k0 += 64) {
#pragma unroll
    for (int i = 0; i < 4; ++i) {
      int u = t + i * 256;
      int row = u >> 3, g = (u & 7) ^ (row & 7);
      gl2lds16(Aout + (m0 + row) * 256 + k0 + g * 8, &At[u * 8]);
      gl2lds16(WT + (n0 + row) * 256 + k0 + g * 8, &Bt[u * 8]);
    }
    __syncthreads();
#pragma unroll
    for (int ds = 0; ds < 2; ++ds) {
      bf16x8 af[4], bfr[4];
#pragma unroll
      for (int m = 0; m < 4; ++m)
        af[m] = *(const bf16x8*)(&At[(wm * 64 + m * 16 + lr) * 64 + (((ds << 2) | lg) ^ (lr & 7)) * 8]);
#pragma unroll
      for (int n = 0; n < 4; ++n)
        bfr[n] = *(const bf16x8*)(&Bt[(wn * 64 + n * 16 + lr) * 64 + (((ds << 2) | lg) ^ (lr & 7)) * 8]);
#pragma unroll
      for (int m = 0; m < 4; ++m)
#pragma unroll
        for (int n = 0; n < 4; ++n)
          acc[m][n] = mfma16(af[m], bfr[n], acc[m][n]);
    }
    __syncthreads();
  }

#pragma unroll
  for (int n = 0; n < 4; ++n) {
    int col = n0 + wn * 64 + n * 16 + lr;
    float bb = bo[col];
#pragma unroll
    for (int m = 0; m < 4; ++m) {
      int rowb = m0 + wm * 64 + m * 16 + lg * 4;
#pragma unroll
      for (int r = 0; r < 4; ++r)
        out[(rowb + r) * 256 + col] = acc[m][n][r] + bb;
    }
  }
}

extern "C" void kernel_launch(void* const* d_in, const int* in_sizes, int n_in,
                              void* d_out, int out_size, void* d_ws, size_t ws_size,
                              hipStream_t stream) {
  const float* v    = (const float*)d_in[0];
  const float* k    = (const float*)d_in[1];
  const float* q    = (const float*)d_in[2];
  const float* mask = (const float*)d_in[3];
  const float* wq   = (const float*)d_in[4];
  const float* bq   = (const float*)d_in[5];
  const float* wk   = (const float*)d_in[6];
  const float* bk   = (const float*)d_in[7];
  const float* wv   = (const float*)d_in[8];
  const float* bv   = (const float*)d_in[9];
  const float* wo   = (const float*)d_in[10];
  const float* bo   = (const float*)d_in[11];
  float* out = (float*)d_out;
  char* ws = (char*)d_ws;

  // ws: wt 524288 | mprep 65536 | Qh 8388608 | Kh 8388608 | VhT 8388608 | Aout 8388608
  unsigned short* wt  = (unsigned short*)(ws);
  float*          mp  = (float*)(ws + 524288);
  unsigned short* Qh  = (unsigned short*)(ws + 589824);
  unsigned short* Kh  = (unsigned short*)(ws + 589824 + 8388608);
  unsigned short* VhT = (unsigned short*)(ws + 589824 + 2 * 8388608);
  unsigned short* Ao  = (unsigned short*)(ws + 589824 + 3 * 8388608);

  prep_w<<<dim3(1024), dim3(256), 0, stream>>>(wq, wk, wv, wo, mask, wt, mp);
  gemm_qkv<<<dim3(128, 2, 3), dim3(256), 0, stream>>>(q, k, v, bq, bk, bv, wt, Qh, Kh, VhT);
  attn<<<dim3(32, 32), dim3(256), 0, stream>>>(Qh, Kh, VhT, mp, Ao);
  gemm_out<<<dim3(128, 2), dim3(256), 0, stream>>>(Ao, wt, bo, out);
}

// Round 3
// 116.220 us; speedup vs baseline: 1.6004x; 1.3253x over previous
//
#include <hip/hip_runtime.h>

#define DEV __device__ __forceinline__

typedef __attribute__((ext_vector_type(4))) float f32x4;
typedef __bf16 bf16_t;
typedef __attribute__((ext_vector_type(4))) bf16_t bf16x4;
typedef __attribute__((ext_vector_type(8))) bf16_t bf16x8;
typedef __attribute__((ext_vector_type(8))) unsigned short us8;
typedef __attribute__((ext_vector_type(4))) unsigned short us4;

// B=8, S=2048, D_MODEL=256, H=4, DEPTH=64, BH=32, M=B*S=16384

DEV unsigned short f2bf(float f) {
  bf16_t h = (bf16_t)f;
  return __builtin_bit_cast(unsigned short, h);
}

DEV void gl2lds16(const void* g, void* l) {
  __builtin_amdgcn_global_load_lds(
      (const __attribute__((address_space(1))) unsigned int*)g,
      (__attribute__((address_space(3))) unsigned int*)l, 16, 0, 0);
}

DEV f32x4 mfma16(bf16x8 a, bf16x8 b, f32x4 c) {
  return __builtin_amdgcn_mfma_f32_16x16x32_bf16(a, b, c, 0, 0, 0);
}

// ---- weights: WT[m][n][k] = W[k][n] (bf16); mask prescale ----
__global__ __launch_bounds__(256) void prep_w(
    const float* __restrict__ wq, const float* __restrict__ wk,
    const float* __restrict__ wv, const float* __restrict__ wo,
    const float* __restrict__ mask,
    unsigned short* __restrict__ wt, float* __restrict__ mprep) {
  int t = blockIdx.x * 256 + threadIdx.x;   // 0 .. 262143
  if (t < 16384) mprep[t] = mask[t] * -1.442695041e9f;   // *(-1e9)*log2(e)
  int m = t >> 16;
  int i = t & 65535;
  int n = i >> 8, k = i & 255;
  const float* W = (m == 0) ? wq : (m == 1) ? wk : (m == 2) ? wv : wo;
  wt[m * 65536 + n * 256 + k] = f2bf(W[k * 256 + n]);
}

// ---- QKV projection GEMM: [128 rows][64 k] swizzled tiles, BK=64 ----
__global__ __launch_bounds__(256) void gemm_qkv(
    const float* __restrict__ Aq, const float* __restrict__ Ak, const float* __restrict__ Av,
    const float* __restrict__ bq, const float* __restrict__ bk, const float* __restrict__ bv,
    const unsigned short* __restrict__ wt,
    unsigned short* __restrict__ Qh, unsigned short* __restrict__ Kh,
    unsigned short* __restrict__ VhT) {
  __shared__ __align__(16) unsigned short At[128 * 64];
  __shared__ __align__(16) unsigned short Bt[128 * 64];
  const int p = blockIdx.z;
  const float* A    = (p == 0) ? Aq : (p == 1) ? Ak : Av;
  const float* bias = (p == 0) ? bq : (p == 1) ? bk : bv;
  const unsigned short* WT = wt + p * 65536;
  const int m0 = blockIdx.x * 128, n0 = blockIdx.y * 128;
  const int t = threadIdx.x, lane = t & 63;
  const int wid = t >> 6, wm = wid >> 1, wn = wid & 1;
  const int lr = lane & 15, lg = lane >> 4;

  f32x4 acc[4][4] = {};

  for (int k0 = 0; k0 < 256; k0 += 64) {
#pragma unroll
    for (int i = 0; i < 4; ++i) {
      int u = t + i * 256;
      int row = u >> 3, un = u & 7;
      const float* src = A + (m0 + row) * 256 + k0 + un * 8;
      f32x4 x0 = *(const f32x4*)src;
      f32x4 x1 = *(const f32x4*)(src + 4);
      us8 pk;
      pk[0] = f2bf(x0[0]); pk[1] = f2bf(x0[1]); pk[2] = f2bf(x0[2]); pk[3] = f2bf(x0[3]);
      pk[4] = f2bf(x1[0]); pk[5] = f2bf(x1[1]); pk[6] = f2bf(x1[2]); pk[7] = f2bf(x1[3]);
      *(us8*)(&At[row * 64 + (un ^ (row & 7)) * 8]) = pk;
    }
#pragma unroll
    for (int i = 0; i < 4; ++i) {
      int u = t + i * 256;
      int row = u >> 3, g = (u & 7) ^ (row & 7);
      gl2lds16(WT + (n0 + row) * 256 + k0 + g * 8, &Bt[u * 8]);
    }
    __syncthreads();
#pragma unroll
    for (int ds = 0; ds < 2; ++ds) {
      bf16x8 af[4], bfr[4];
#pragma unroll
      for (int m = 0; m < 4; ++m)
        af[m] = *(const bf16x8*)(&At[(wm * 64 + m * 16 + lr) * 64 + (((ds << 2) | lg) ^ (lr & 7)) * 8]);
#pragma unroll
      for (int n = 0; n < 4; ++n)
        bfr[n] = *(const bf16x8*)(&Bt[(wn * 64 + n * 16 + lr) * 64 + (((ds << 2) | lg) ^ (lr & 7)) * 8]);
#pragma unroll
      for (int m = 0; m < 4; ++m)
#pragma unroll
        for (int n = 0; n < 4; ++n)
          acc[m][n] = mfma16(af[m], bfr[n], acc[m][n]);
    }
    __syncthreads();
  }

#pragma unroll
  for (int n = 0; n < 4; ++n) {
    int col = n0 + wn * 64 + n * 16 + lr;
    float bb = bias[col];
    int h = col >> 6, d = col & 63;
#pragma unroll
    for (int m = 0; m < 4; ++m) {
      int rowb = m0 + wm * 64 + m * 16 + lg * 4;
#pragma unroll
      for (int r = 0; r < 4; ++r) {
        int srow = rowb + r;
        int b = srow >> 11, s = srow & 2047;
        int bh = b * 4 + h;
        unsigned short val = f2bf(acc[m][n][r] + bb);
        if (p == 0)      Qh[(bh * 2048 + s) * 64 + d] = val;
        else if (p == 1) Kh[(bh * 2048 + s) * 64 + d] = val;
        else             VhT[((bh * 64 + d) * 2048) + s] = val;
      }
    }
  }
}

// ---- fused flash attention: swapped QK^T, in-register P, per-lane softmax ----
__global__ __launch_bounds__(256) void attn(
    const unsigned short* __restrict__ Qh, const unsigned short* __restrict__ Kh,
    const unsigned short* __restrict__ VhT, const float* __restrict__ mprep,
    unsigned short* __restrict__ Aout) {
  __shared__ __align__(16) unsigned short Kt[2][4096];
  __shared__ __align__(16) unsigned short Vt[2][4096];
  const int bh = blockIdx.y;
  const int q0 = blockIdx.x * 64;
  const int t = threadIdx.x, lane = t & 63, wid = t >> 6;
  const int lr = lane & 15, lg = lane >> 4;
  const int qrow = q0 + wid * 16;
  const unsigned short* Kbase = Kh + bh * 131072;
  const unsigned short* Vbase = VhT + bh * 131072;
  const float* mrow = mprep + (bh >> 2) * 2048;
  const int lx = lr & 7;          // swizzle xor
  const int lgh = lg >> 1, lgo = (lg & 1) * 4;

  // Q as B-operand: B[k][col=q=lr], k = ds*32 + lg*8 + j
  bf16x8 qf[2];
#pragma unroll
  for (int ds = 0; ds < 2; ++ds)
    qf[ds] = *(const bf16x8*)(Qh + (bh * 2048 + qrow + lr) * 64 + ds * 32 + lg * 8);

  f32x4 accO[4] = {};           // accO[db][r] = O[q=lr][d=db*16+lg*4+r]
  float mrun = -3.0e38f, lrun = 0.f;

#define STAGE(buf, kv)                                                        \
  {                                                                           \
    _Pragma("unroll")                                                         \
    for (int i = 0; i < 2; ++i) {                                             \
      int u = t + i * 256;                                                    \
      int row = u >> 3, g = (u & 7) ^ (row & 7);                              \
      gl2lds16(Kbase + ((kv) + row) * 64 + g * 8, &Kt[buf][u * 8]);           \
      gl2lds16(Vbase + row * 2048 + (kv) + g * 8, &Vt[buf][u * 8]);           \
    }                                                                         \
  }

  STAGE(0, 0)
  __syncthreads();
  int cur = 0;

  for (int kv0 = 0; kv0 < 2048; kv0 += 64) {
    if (kv0 + 64 < 2048) STAGE(cur ^ 1, kv0 + 64)

    // S^T = K Q^T : accS[kb][r] = S[q=lr][k = kv0 + kb*16 + lg*4 + r]
    f32x4 accS[4] = {};
    __builtin_amdgcn_s_setprio(1);
#pragma unroll
    for (int kb = 0; kb < 4; ++kb)
#pragma unroll
      for (int ds = 0; ds < 2; ++ds) {
        bf16x8 kf = *(const bf16x8*)(&Kt[cur][((kb * 16 + lr) << 3 | (((ds << 2) | lg) ^ lx)) * 8]);
        accS[kb] = mfma16(kf, qf[ds], accS[kb]);
      }
    __builtin_amdgcn_s_setprio(0);

    // logits in log2 domain (per-lane row q=lr)
    f32x4 sv[4];
#pragma unroll
    for (int kb = 0; kb < 4; ++kb) {
      f32x4 mk = *(const f32x4*)(mrow + kv0 + kb * 16 + lg * 4);
      sv[kb] = accS[kb] * 0.1803368801f + mk;
    }
    float mx0 = fmaxf(fmaxf(sv[0][0], sv[0][1]), fmaxf(sv[0][2], sv[0][3]));
    float mx1 = fmaxf(fmaxf(sv[1][0], sv[1][1]), fmaxf(sv[1][2], sv[1][3]));
    float mx2 = fmaxf(fmaxf(sv[2][0], sv[2][1]), fmaxf(sv[2][2], sv[2][3]));
    float mx3 = fmaxf(fmaxf(sv[3][0], sv[3][1]), fmaxf(sv[3][2], sv[3][3]));
    float mx = fmaxf(fmaxf(mx0, mx1), fmaxf(mx2, mx3));
    mx = fmaxf(mx, __shfl_xor(mx, 16));
    mx = fmaxf(mx, __shfl_xor(mx, 32));
    float mnew = fmaxf(mrun, mx);
    float al = __builtin_amdgcn_exp2f(mrun - mnew);
    mrun = mnew;

    float px[4][4];
    float lsum = 0.f;
#pragma unroll
    for (int kb = 0; kb < 4; ++kb) {
      float s = 0.f;
#pragma unroll
      for (int r = 0; r < 4; ++r) {
        px[kb][r] = __builtin_amdgcn_exp2f(sv[kb][r] - mnew);
        s += px[kb][r];
      }
      lsum += s;
    }
    lsum += __shfl_xor(lsum, 16);
    lsum += __shfl_xor(lsum, 32);
    lrun = lrun * al + lsum;
#pragma unroll
    for (int db = 0; db < 4; ++db) accO[db] *= al;

    // P fragments, fully lane-local (k-permutation matched by V reads)
    bf16x8 pf[2];
#pragma unroll
    for (int ks = 0; ks < 2; ++ks) {
      bf16x8 p;
#pragma unroll
      for (int r = 0; r < 4; ++r) {
        p[r]     = (bf16_t)px[2 * ks][r];
        p[r + 4] = (bf16_t)px[2 * ks + 1][r];
      }
      pf[ks] = p;
    }

    // O^T += V^T P^T   (A = V^T rows d, k permuted; B = pf)
    __builtin_amdgcn_s_setprio(1);
#pragma unroll
    for (int ks = 0; ks < 2; ++ks)
#pragma unroll
      for (int db = 0; db < 4; ++db) {
        int row = db * 16 + lr;
        int u0 = (row << 3) | (((ks << 2) | lgh) ^ lx);
        int u1 = (row << 3) | (((ks << 2) | 2 | lgh) ^ lx);
        bf16x4 v0 = *(const bf16x4*)(&Vt[cur][u0 * 8 + lgo]);
        bf16x4 v1 = *(const bf16x4*)(&Vt[cur][u1 * 8 + lgo]);
        bf16x8 vf = __builtin_shufflevector(v0, v1, 0, 1, 2, 3, 4, 5, 6, 7);
        accO[db] = mfma16(vf, pf[ks], accO[db]);
      }
    __builtin_amdgcn_s_setprio(0);

    __syncthreads();   // drains prefetch vmcnt + releases cur buf
    cur ^= 1;
  }
#undef STAGE

  const int b = bh >> 2, h = bh & 3;
  const float inv = __builtin_amdgcn_rcpf(lrun);
  const int q = qrow + lr;
#pragma unroll
  for (int db = 0; db < 4; ++db) {
    us4 o;
#pragma unroll
    for (int r = 0; r < 4; ++r) o[r] = f2bf(accO[db][r] * inv);
    *(us4*)(&Aout[(b * 2048 + q) * 256 + h * 64 + db * 16 + lg * 4]) = o;
  }
}

// ---- output projection: out = Aout(bf16) * Wo + bo (f32 out) ----
__global__ __launch_bounds__(256) void gemm_out(
    const unsigned short* __restrict__ Aout, const unsigned short* __restrict__ wt,
    const float* __restrict__ bo, float* __restrict__ out) {
  __shared__ __align__(16) unsigned short At[128 * 64];
  __shared__ __align__(16) unsigned short Bt[128 * 64];
  const unsigned short* WT = wt + 3 * 65536;
  const int m0 = blockIdx.x * 128, n0 = blockIdx.y * 128;
  const int t = threadIdx.x, lane = t & 63;
  const int wid = t >> 6, wm = wid >> 1, wn = wid & 1;
  const int lr = lane & 15, lg = lane >> 4;

  f32x4 acc[4][4] = {};

  for (int k0 = 0; k0 < 256; k0 += 64) {
#pragma unroll
    for (int i = 0; i < 4; ++i) {
      int u = t + i * 256;
      int row = u >> 3, g = (u & 7) ^ (row & 7);
      gl2lds16(Aout + (m0 + row) * 256 + k0 + g * 8, &At[u * 8]);
      gl2lds16(WT + (n0 + row) * 256 + k0 + g * 8, &Bt[u * 8]);
    }
    __syncthreads();
#pragma unroll
    for (int ds = 0; ds < 2; ++ds) {
      bf16x8 af[4], bfr[4];
#pragma unroll
      for (int m = 0; m < 4; ++m)
        af[m] = *(const bf16x8*)(&At[(wm * 64 + m * 16 + lr) * 64 + (((ds << 2) | lg) ^ (lr & 7)) * 8]);
#pragma unroll
      for (int n = 0; n < 4; ++n)
        bfr[n] = *(const bf16x8*)(&Bt[(wn * 64 + n * 16 + lr) * 64 + (((ds << 2) | lg) ^ (lr & 7)) * 8]);
#pragma unroll
      for (int m = 0; m < 4; ++m)
#pragma unroll
        for (int n = 0; n < 4; ++n)
          acc[m][n] = mfma16(af[m], bfr[n], acc[m][n]);
    }
    __syncthreads();
  }

#pragma unroll
  for (int n = 0; n < 4; ++n) {
    int col = n0 + wn * 64 + n * 16 + lr;
    float bb = bo[col];
#pragma unroll
    for (int m = 0; m < 4; ++m) {
      int rowb = m0 + wm * 64 + m * 16 + lg * 4;
#pragma unroll
      for (int r = 0; r < 4; ++r)
        out[(rowb + r) * 256 + col] = acc[m][n][r] + bb;
    }
  }
}

extern "C" void kernel_launch(void* const* d_in, const int* in_sizes, int n_in,
                              void* d_out, int out_size, void* d_ws, size_t ws_size,
                              hipStream_t stream) {
  const float* v    = (const float*)d_in[0];
  const float* k    = (const float*)d_in[1];
  const float* q    = (const float*)d_in[2];
  const float* mask = (const float*)d_in[3];
  const float* wq   = (const float*)d_in[4];
  const float* bq   = (const float*)d_in[5];
  const float* wk   = (const float*)d_in[6];
  const float* bk   = (const float*)d_in[7];
  const float* wv   = (const float*)d_in[8];
  const float* bv   = (const float*)d_in[9];
  const float* wo   = (const float*)d_in[10];
  const float* bo   = (const float*)d_in[11];
  float* out = (float*)d_out;
  char* ws = (char*)d_ws;

  // ws: wt 524288 | mprep 65536 | Qh 8388608 | Kh 8388608 | VhT 8388608 | Aout 8388608
  unsigned short* wt  = (unsigned short*)(ws);
  float*          mp  = (float*)(ws + 524288);
  unsigned short* Qh  = (unsigned short*)(ws + 589824);
  unsigned short* Kh  = (unsigned short*)(ws + 589824 + 8388608);
  unsigned short* VhT = (unsigned short*)(ws + 589824 + 2 * 8388608);
  unsigned short* Ao  = (unsigned short*)(ws + 589824 + 3 * 8388608);

  prep_w<<<dim3(1024), dim3(256), 0, stream>>>(wq, wk, wv, wo, mask, wt, mp);
  gemm_qkv<<<dim3(128, 2, 3), dim3(256), 0, stream>>>(q, k, v, bq, bk, bv, wt, Qh, Kh, VhT);
  attn<<<dim3(32, 32), dim3(256), 0, stream>>>(Qh, Kh, VhT, mp, Ao);
  gemm_out<<<dim3(128, 2), dim3(256), 0, stream>>>(Ao, wt, bo, out);
}

// Round 4
// 72.202 us; speedup vs baseline: 2.5762x; 1.6096x over previous
//
#include <hip/hip_runtime.h>

#define DEV __device__ __forceinline__

typedef __attribute__((ext_vector_type(4))) float f32x4;
typedef __bf16 bf16_t;
typedef __attribute__((ext_vector_type(4))) bf16_t bf16x4;
typedef __attribute__((ext_vector_type(8))) bf16_t bf16x8;
typedef __attribute__((ext_vector_type(8))) unsigned short us8;
typedef __attribute__((ext_vector_type(4))) unsigned short us4;

// B=8, S=2048, D_MODEL=256, H=4, DEPTH=64, BH=32, M=B*S=16384

DEV unsigned short f2bf(float f) {
  bf16_t h = (bf16_t)f;
  return __builtin_bit_cast(unsigned short, h);
}

DEV void gl2lds16(const void* g, void* l) {
  __builtin_amdgcn_global_load_lds(
      (const __attribute__((address_space(1))) unsigned int*)g,
      (__attribute__((address_space(3))) unsigned int*)l, 16, 0, 0);
}

DEV f32x4 mfma16(bf16x8 a, bf16x8 b, f32x4 c) {
  return __builtin_amdgcn_mfma_f32_16x16x32_bf16(a, b, c, 0, 0, 0);
}

// ---- weights: WT[m][n][k] = W[k][n] (bf16); mask prescale; tile prune list ----
// Branch-and-bound pruning: tile t of batch b can influence softmax only if
//   -1.443e9*tilemin[t] + BQK >= -1.443e9*minm - BQK - 40   (BQK=1000 bounds |0.18*qk|)
// i.e. tilemin[t] < minm + 1.45e-6. Sound for ANY data; degrades to full loop.
__global__ __launch_bounds__(256) void prep_w(
    const float* __restrict__ wq, const float* __restrict__ wk,
    const float* __restrict__ wv, const float* __restrict__ wo,
    const float* __restrict__ mask,
    unsigned short* __restrict__ wt, float* __restrict__ mprep,
    int* __restrict__ proc) {
  int t = blockIdx.x * 256 + threadIdx.x;   // 0 .. 262143
  if (t < 16384) mprep[t] = mask[t] * -1.442695041e9f;   // *(-1e9)*log2(e)
  int m = t >> 16;
  int i = t & 65535;
  int n = i >> 8, k = i & 255;
  const float* W = (m == 0) ? wq : (m == 1) ? wk : (m == 2) ? wv : wo;
  wt[m * 65536 + n * 256 + k] = f2bf(W[k * 256 + n]);

  if (blockIdx.x == 0) {
    __shared__ float tm[256];
    int tid = threadIdx.x;                       // b = tid>>5, tile = tid&31
    const float* mr = mask + (tid >> 5) * 2048 + (tid & 31) * 64;
    float mn = 1e30f;
    for (int j = 0; j < 64; ++j) mn = fminf(mn, mr[j]);
    tm[tid] = mn;
    __syncthreads();
    if (tid < 8) {
      int base = tid * 33, cnt = 0;
      float minm = 1e30f;
      for (int tl = 0; tl < 32; ++tl) {
        float v = tm[tid * 32 + tl];
        if (v < minm + 1.45e-6f) { proc[base + 1 + cnt] = tl; ++cnt; }
        minm = fminf(minm, v);
      }
      proc[base] = cnt;
    }
  }
}

// ---- QKV projection GEMM: [128 rows][64 k] swizzled tiles, BK=64 ----
__global__ __launch_bounds__(256) void gemm_qkv(
    const float* __restrict__ Aq, const float* __restrict__ Ak, const float* __restrict__ Av,
    const float* __restrict__ bq, const float* __restrict__ bk, const float* __restrict__ bv,
    const unsigned short* __restrict__ wt,
    unsigned short* __restrict__ Qh, unsigned short* __restrict__ Kh,
    unsigned short* __restrict__ VhT) {
  __shared__ __align__(16) unsigned short At[128 * 64];
  __shared__ __align__(16) unsigned short Bt[128 * 64];
  const int p = blockIdx.z;
  const float* A    = (p == 0) ? Aq : (p == 1) ? Ak : Av;
  const float* bias = (p == 0) ? bq : (p == 1) ? bk : bv;
  const unsigned short* WT = wt + p * 65536;
  const int m0 = blockIdx.x * 128, n0 = blockIdx.y * 128;
  const int t = threadIdx.x, lane = t & 63;
  const int wid = t >> 6, wm = wid >> 1, wn = wid & 1;
  const int lr = lane & 15, lg = lane >> 4;

  f32x4 acc[4][4] = {};

  for (int k0 = 0; k0 < 256; k0 += 64) {
#pragma unroll
    for (int i = 0; i < 4; ++i) {
      int u = t + i * 256;
      int row = u >> 3, un = u & 7;
      const float* src = A + (m0 + row) * 256 + k0 + un * 8;
      f32x4 x0 = *(const f32x4*)src;
      f32x4 x1 = *(const f32x4*)(src + 4);
      us8 pk;
      pk[0] = f2bf(x0[0]); pk[1] = f2bf(x0[1]); pk[2] = f2bf(x0[2]); pk[3] = f2bf(x0[3]);
      pk[4] = f2bf(x1[0]); pk[5] = f2bf(x1[1]); pk[6] = f2bf(x1[2]); pk[7] = f2bf(x1[3]);
      *(us8*)(&At[row * 64 + (un ^ (row & 7)) * 8]) = pk;
    }
#pragma unroll
    for (int i = 0; i < 4; ++i) {
      int u = t + i * 256;
      int row = u >> 3, g = (u & 7) ^ (row & 7);
      gl2lds16(WT + (n0 + row) * 256 + k0 + g * 8, &Bt[u * 8]);
    }
    __syncthreads();
#pragma unroll
    for (int ds = 0; ds < 2; ++ds) {
      bf16x8 af[4], bfr[4];
#pragma unroll
      for (int m = 0; m < 4; ++m)
        af[m] = *(const bf16x8*)(&At[(wm * 64 + m * 16 + lr) * 64 + (((ds << 2) | lg) ^ (lr & 7)) * 8]);
#pragma unroll
      for (int n = 0; n < 4; ++n)
        bfr[n] = *(const bf16x8*)(&Bt[(wn * 64 + n * 16 + lr) * 64 + (((ds << 2) | lg) ^ (lr & 7)) * 8]);
#pragma unroll
      for (int m = 0; m < 4; ++m)
#pragma unroll
        for (int n = 0; n < 4; ++n)
          acc[m][n] = mfma16(af[m], bfr[n], acc[m][n]);
    }
    __syncthreads();
  }

#pragma unroll
  for (int n = 0; n < 4; ++n) {
    int col = n0 + wn * 64 + n * 16 + lr;
    float bb = bias[col];
    int h = col >> 6, d = col & 63;
#pragma unroll
    for (int m = 0; m < 4; ++m) {
      int rowb = m0 + wm * 64 + m * 16 + lg * 4;
#pragma unroll
      for (int r = 0; r < 4; ++r) {
        int srow = rowb + r;
        int b = srow >> 11, s = srow & 2047;
        int bh = b * 4 + h;
        unsigned short val = f2bf(acc[m][n][r] + bb);
        if (p == 0)      Qh[(bh * 2048 + s) * 64 + d] = val;
        else if (p == 1) Kh[(bh * 2048 + s) * 64 + d] = val;
        else             VhT[((bh * 64 + d) * 2048) + s] = val;
      }
    }
  }
}

// ---- fused flash attention: pruned tile list, swapped QK^T, in-register P ----
__global__ __launch_bounds__(256) void attn(
    const unsigned short* __restrict__ Qh, const unsigned short* __restrict__ Kh,
    const unsigned short* __restrict__ VhT, const float* __restrict__ mprep,
    const int* __restrict__ proc,
    unsigned short* __restrict__ Aout) {
  __shared__ __align__(16) unsigned short Kt[2][4096];
  __shared__ __align__(16) unsigned short Vt[2][4096];
  const int bh = blockIdx.y;
  const int q0 = blockIdx.x * 64;
  const int t = threadIdx.x, lane = t & 63, wid = t >> 6;
  const int lr = lane & 15, lg = lane >> 4;
  const int qrow = q0 + wid * 16;
  const unsigned short* Kbase = Kh + bh * 131072;
  const unsigned short* Vbase = VhT + bh * 131072;
  const float* mrow = mprep + (bh >> 2) * 2048;
  const int* plist = proc + (bh >> 2) * 33;
  const int lx = lr & 7;          // swizzle xor
  const int lgh = lg >> 1, lgo = (lg & 1) * 4;

  // Q as B-operand: B[k][col=q=lr], k = ds*32 + lg*8 + j
  bf16x8 qf[2];
#pragma unroll
  for (int ds = 0; ds < 2; ++ds)
    qf[ds] = *(const bf16x8*)(Qh + (bh * 2048 + qrow + lr) * 64 + ds * 32 + lg * 8);

  f32x4 accO[4] = {};           // accO[db][r] = O[q=lr][d=db*16+lg*4+r]
  float mrun = -3.0e38f, lrun = 0.f;

#define STAGE(buf, kv)                                                        \
  {                                                                           \
    _Pragma("unroll")                                                         \
    for (int i = 0; i < 2; ++i) {                                             \
      int u = t + i * 256;                                                    \
      int row = u >> 3, g = (u & 7) ^ (row & 7);                              \
      gl2lds16(Kbase + ((kv) + row) * 64 + g * 8, &Kt[buf][u * 8]);           \
      gl2lds16(Vbase + row * 2048 + (kv) + g * 8, &Vt[buf][u * 8]);           \
    }                                                                         \
  }

  const int cnt = plist[0];                 // block-uniform
  STAGE(0, plist[1] * 64)
  __syncthreads();
  int cur = 0;

  for (int j = 0; j < cnt; ++j) {
    const int kv0 = plist[1 + j] * 64;
    if (j + 1 < cnt) STAGE(cur ^ 1, plist[2 + j] * 64)

    // S^T = K Q^T : accS[kb][r] = S[q=lr][k = kv0 + kb*16 + lg*4 + r]
    f32x4 accS[4] = {};
    __builtin_amdgcn_s_setprio(1);
#pragma unroll
    for (int kb = 0; kb < 4; ++kb)
#pragma unroll
      for (int ds = 0; ds < 2; ++ds) {
        bf16x8 kf = *(const bf16x8*)(&Kt[cur][((kb * 16 + lr) << 3 | (((ds << 2) | lg) ^ lx)) * 8]);
        accS[kb] = mfma16(kf, qf[ds], accS[kb]);
      }
    __builtin_amdgcn_s_setprio(0);

    // logits in log2 domain (per-lane row q=lr)
    f32x4 sv[4];
#pragma unroll
    for (int kb = 0; kb < 4; ++kb) {
      f32x4 mk = *(const f32x4*)(mrow + kv0 + kb * 16 + lg * 4);
      sv[kb] = accS[kb] * 0.1803368801f + mk;
    }
    float mx0 = fmaxf(fmaxf(sv[0][0], sv[0][1]), fmaxf(sv[0][2], sv[0][3]));
    float mx1 = fmaxf(fmaxf(sv[1][0], sv[1][1]), fmaxf(sv[1][2], sv[1][3]));
    float mx2 = fmaxf(fmaxf(sv[2][0], sv[2][1]), fmaxf(sv[2][2], sv[2][3]));
    float mx3 = fmaxf(fmaxf(sv[3][0], sv[3][1]), fmaxf(sv[3][2], sv[3][3]));
    float mx = fmaxf(fmaxf(mx0, mx1), fmaxf(mx2, mx3));
    mx = fmaxf(mx, __shfl_xor(mx, 16));
    mx = fmaxf(mx, __shfl_xor(mx, 32));
    float mnew = fmaxf(mrun, mx);
    float al = __builtin_amdgcn_exp2f(mrun - mnew);
    mrun = mnew;

    float px[4][4];
    float lsum = 0.f;
#pragma unroll
    for (int kb = 0; kb < 4; ++kb) {
      float s = 0.f;
#pragma unroll
      for (int r = 0; r < 4; ++r) {
        px[kb][r] = __builtin_amdgcn_exp2f(sv[kb][r] - mnew);
        s += px[kb][r];
      }
      lsum += s;
    }
    lsum += __shfl_xor(lsum, 16);
    lsum += __shfl_xor(lsum, 32);
    lrun = lrun * al + lsum;
#pragma unroll
    for (int db = 0; db < 4; ++db) accO[db] *= al;

    // P fragments, fully lane-local (k-permutation matched by V reads)
    bf16x8 pf[2];
#pragma unroll
    for (int ks = 0; ks < 2; ++ks) {
      bf16x8 p;
#pragma unroll
      for (int r = 0; r < 4; ++r) {
        p[r]     = (bf16_t)px[2 * ks][r];
        p[r + 4] = (bf16_t)px[2 * ks + 1][r];
      }
      pf[ks] = p;
    }

    // O^T += V^T P^T   (A = V^T rows d, k permuted; B = pf)
    __builtin_amdgcn_s_setprio(1);
#pragma unroll
    for (int ks = 0; ks < 2; ++ks)
#pragma unroll
      for (int db = 0; db < 4; ++db) {
        int row = db * 16 + lr;
        int u0 = (row << 3) | (((ks << 2) | lgh) ^ lx);
        int u1 = (row << 3) | (((ks << 2) | 2 | lgh) ^ lx);
        bf16x4 v0 = *(const bf16x4*)(&Vt[cur][u0 * 8 + lgo]);
        bf16x4 v1 = *(const bf16x4*)(&Vt[cur][u1 * 8 + lgo]);
        bf16x8 vf = __builtin_shufflevector(v0, v1, 0, 1, 2, 3, 4, 5, 6, 7);
        accO[db] = mfma16(vf, pf[ks], accO[db]);
      }
    __builtin_amdgcn_s_setprio(0);

    __syncthreads();   // drains prefetch vmcnt + releases cur buf
    cur ^= 1;
  }
#undef STAGE

  const int b = bh >> 2, h = bh & 3;
  const float inv = __builtin_amdgcn_rcpf(lrun);
  const int q = qrow + lr;
#pragma unroll
  for (int db = 0; db < 4; ++db) {
    us4 o;
#pragma unroll
    for (int r = 0; r < 4; ++r) o[r] = f2bf(accO[db][r] * inv);
    *(us4*)(&Aout[(b * 2048 + q) * 256 + h * 64 + db * 16 + lg * 4]) = o;
  }
}

// ---- output projection: out = Aout(bf16) * Wo + bo (f32 out) ----
__global__ __launch_bounds__(256) void gemm_out(
    const unsigned short* __restrict__ Aout, const unsigned short* __restrict__ wt,
    const float* __restrict__ bo, float* __restrict__ out) {
  __shared__ __align__(16) unsigned short At[128 * 64];
  __shared__ __align__(16) unsigned short Bt[128 * 64];
  const unsigned short* WT = wt + 3 * 65536;
  const int m0 = blockIdx.x * 128, n0 = blockIdx.y * 128;
  const int t = threadIdx.x, lane = t & 63;
  const int wid = t >> 6, wm = wid >> 1, wn = wid & 1;
  const int lr = lane & 15, lg = lane >> 4;

  f32x4 acc[4][4] = {};

  for (int k0 = 0; k0 < 256; k0 += 64) {
#pragma unroll
    for (int i = 0; i < 4; ++i) {
      int u = t + i * 256;
      int row = u >> 3, g = (u & 7) ^ (row & 7);
      gl2lds16(Aout + (m0 + row) * 256 + k0 + g * 8, &At[u * 8]);
      gl2lds16(WT + (n0 + row) * 256 + k0 + g * 8, &Bt[u * 8]);
    }
    __syncthreads();
#pragma unroll
    for (int ds = 0; ds < 2; ++ds) {
      bf16x8 af[4], bfr[4];
#pragma unroll
      for (int m = 0; m < 4; ++m)
        af[m] = *(const bf16x8*)(&At[(wm * 64 + m * 16 + lr) * 64 + (((ds << 2) | lg) ^ (lr & 7)) * 8]);
#pragma unroll
      for (int n = 0; n < 4; ++n)
        bfr[n] = *(const bf16x8*)(&Bt[(wn * 64 + n * 16 + lr) * 64 + (((ds << 2) | lg) ^ (lr & 7)) * 8]);
#pragma unroll
      for (int m = 0; m < 4; ++m)
#pragma unroll
        for (int n = 0; n < 4; ++n)
          acc[m][n] = mfma16(af[m], bfr[n], acc[m][n]);
    }
    __syncthreads();
  }

#pragma unroll
  for (int n = 0; n < 4; ++n) {
    int col = n0 + wn * 64 + n * 16 + lr;
    float bb = bo[col];
#pragma unroll
    for (int m = 0; m < 4; ++m) {
      int rowb = m0 + wm * 64 + m * 16 + lg * 4;
#pragma unroll
      for (int r = 0; r < 4; ++r)
        out[(rowb + r) * 256 + col] = acc[m][n][r] + bb;
    }
  }
}

extern "C" void kernel_launch(void* const* d_in, const int* in_sizes, int n_in,
                              void* d_out, int out_size, void* d_ws, size_t ws_size,
                              hipStream_t stream) {
  const float* v    = (const float*)d_in[0];
  const float* k    = (const float*)d_in[1];
  const float* q    = (const float*)d_in[2];
  const float* mask = (const float*)d_in[3];
  const float* wq   = (const float*)d_in[4];
  const float* bq   = (const float*)d_in[5];
  const float* wk   = (const float*)d_in[6];
  const float* bk   = (const float*)d_in[7];
  const float* wv   = (const float*)d_in[8];
  const float* bv   = (const float*)d_in[9];
  const float* wo   = (const float*)d_in[10];
  const float* bo   = (const float*)d_in[11];
  float* out = (float*)d_out;
  char* ws = (char*)d_ws;

  // ws: wt 524288 | mprep 65536 | proc 4096 | Qh | Kh | VhT | Aout (8 MB each)
  unsigned short* wt  = (unsigned short*)(ws);
  float*          mp  = (float*)(ws + 524288);
  int*            pr  = (int*)(ws + 589824);
  unsigned short* Qh  = (unsigned short*)(ws + 593920);
  unsigned short* Kh  = (unsigned short*)(ws + 593920 + 8388608);
  unsigned short* VhT = (unsigned short*)(ws + 593920 + 2 * 8388608);
  unsigned short* Ao  = (unsigned short*)(ws + 593920 + 3 * 8388608);

  prep_w<<<dim3(1024), dim3(256), 0, stream>>>(wq, wk, wv, wo, mask, wt, mp, pr);
  gemm_qkv<<<dim3(128, 2, 3), dim3(256), 0, stream>>>(q, k, v, bq, bk, bv, wt, Qh, Kh, VhT);
  attn<<<dim3(32, 32), dim3(256), 0, stream>>>(Qh, Kh, VhT, mp, pr, Ao);
  gemm_out<<<dim3(128, 2), dim3(256), 0, stream>>>(Ao, wt, bo, out);
}

// Round 5
// 69.949 us; speedup vs baseline: 2.6592x; 1.0322x over previous
//
#include <hip/hip_runtime.h>

#define DEV __device__ __forceinline__

typedef __attribute__((ext_vector_type(4))) float f32x4;
typedef __bf16 bf16_t;
typedef __attribute__((ext_vector_type(4))) bf16_t bf16x4;
typedef __attribute__((ext_vector_type(8))) bf16_t bf16x8;
typedef __attribute__((ext_vector_type(8))) unsigned short us8;
typedef __attribute__((ext_vector_type(4))) unsigned short us4;

// B=8, S=2048, D_MODEL=256, H=4, DEPTH=64, BH=32, M=B*S=16384

DEV unsigned short f2bf(float f) {
  bf16_t h = (bf16_t)f;
  return __builtin_bit_cast(unsigned short, h);
}

DEV void gl2lds16(const void* g, void* l) {
  __builtin_amdgcn_global_load_lds(
      (const __attribute__((address_space(1))) unsigned int*)g,
      (__attribute__((address_space(3))) unsigned int*)l, 16, 0, 0);
}

DEV f32x4 mfma16(bf16x8 a, bf16x8 b, f32x4 c) {
  return __builtin_amdgcn_mfma_f32_16x16x32_bf16(a, b, c, 0, 0, 0);
}

// ---- prep: W transpose via LDS (blocks 0..63), mask prescale + prune (block 64) ----
// Pruning: tile t of batch b can influence softmax only if
//   tilemin_mask[t] < running_min + 1.45e-6   (sound bound, |0.18*qk|<=1000)
__global__ __launch_bounds__(256) void prep_w(
    const float* __restrict__ wq, const float* __restrict__ wk,
    const float* __restrict__ wv, const float* __restrict__ wo,
    const float* __restrict__ mask,
    unsigned short* __restrict__ wt, float* __restrict__ mprep,
    int* __restrict__ proc) {
  const int t = threadIdx.x;
  if (blockIdx.x < 64) {
    __shared__ float T[64 * 65];
    const int mat = blockIdx.x >> 4, tn = (blockIdx.x >> 2) & 3, tk = blockIdx.x & 3;
    const int n0 = tn * 64, k0 = tk * 64;
    const float* W = (mat == 0) ? wq : (mat == 1) ? wk : (mat == 2) ? wv : wo;
    const int r0 = t >> 4, c = (t & 15) * 4;
#pragma unroll
    for (int i = 0; i < 4; ++i) {
      int rr = r0 + i * 16;                       // k-local row
      f32x4 x = *(const f32x4*)(W + (k0 + rr) * 256 + n0 + c);
#pragma unroll
      for (int j = 0; j < 4; ++j) T[(c + j) * 65 + rr] = x[j];
    }
    __syncthreads();
#pragma unroll
    for (int i = 0; i < 2; ++i) {
      int u = t + i * 256;
      int n = u >> 3, seg = u & 7;
      us8 pk;
#pragma unroll
      for (int j = 0; j < 8; ++j) pk[j] = f2bf(T[n * 65 + seg * 8 + j]);
      *(us8*)(&wt[mat * 65536 + (n0 + n) * 256 + k0 + seg * 8]) = pk;
    }
  } else {
    __shared__ float tm[256];
    const float* mr = mask + t * 64;
    float mn = 1e30f;
#pragma unroll
    for (int j = 0; j < 16; ++j) {
      f32x4 x = *(const f32x4*)(mr + j * 4);
      mn = fminf(mn, fminf(fminf(x[0], x[1]), fminf(x[2], x[3])));
      *(f32x4*)(mprep + t * 64 + j * 4) = x * -1.442695041e9f;
    }
    tm[t] = mn;
    __syncthreads();
    if (t < 8) {
      int base = t * 33, cnt = 0;
      float minm = 1e30f;
      for (int tl = 0; tl < 32; ++tl) {
        float v = tm[t * 32 + tl];
        if (v < minm + 1.45e-6f) { proc[base + 1 + cnt] = tl; ++cnt; }
        minm = fminf(minm, v);
      }
      proc[base] = cnt;
    }
  }
}

// ---- QKV projection GEMM: 64x128 tile, BK=64, dbuf, issue-early/write-late ----
__global__ __launch_bounds__(256) void gemm_qkv(
    const float* __restrict__ Aq, const float* __restrict__ Ak, const float* __restrict__ Av,
    const float* __restrict__ bq, const float* __restrict__ bk, const float* __restrict__ bv,
    const unsigned short* __restrict__ wt,
    unsigned short* __restrict__ Qh, unsigned short* __restrict__ Kh,
    unsigned short* __restrict__ VhT) {
  __shared__ __align__(16) unsigned short At[2][64 * 64];
  __shared__ __align__(16) unsigned short Bt[2][128 * 64];
  const int p = blockIdx.z;
  const float* A    = (p == 0) ? Aq : (p == 1) ? Ak : Av;
  const float* bias = (p == 0) ? bq : (p == 1) ? bk : bv;
  const unsigned short* WT = wt + p * 65536;
  const int m0 = blockIdx.x * 64, n0 = blockIdx.y * 128;
  const int t = threadIdx.x, lane = t & 63;
  const int wid = t >> 6;
  const int lr = lane & 15, lg = lane >> 4;

  // A staging coords: 4 threads/row, 16 k each
  const int ar_row = t >> 2, ar_seg = (t & 3) * 16;
  const float* agp = A + (m0 + ar_row) * 256 + ar_seg;

  f32x4 ar[4];
  f32x4 acc[4][2] = {};

#define ISSUE_A(k0)                                                           \
  { _Pragma("unroll") for (int i = 0; i < 4; ++i)                             \
      ar[i] = *(const f32x4*)(agp + (k0) + i * 4); }
#define ISSUE_B(buf, k0)                                                      \
  { _Pragma("unroll") for (int i = 0; i < 4; ++i) {                           \
      int u = t + i * 256;                                                    \
      int row = u >> 3, g = (u & 7) ^ (row & 7);                              \
      gl2lds16(WT + (n0 + row) * 256 + (k0) + g * 8, &Bt[buf][u * 8]); } }
#define WRITE_A(buf)                                                          \
  { us8 pk0, pk1;                                                             \
    _Pragma("unroll") for (int j = 0; j < 4; ++j) {                           \
      pk0[j] = f2bf(ar[0][j]); pk0[j + 4] = f2bf(ar[1][j]);                   \
      pk1[j] = f2bf(ar[2][j]); pk1[j + 4] = f2bf(ar[3][j]); }                 \
    int un0 = (ar_seg >> 3), base = ar_row * 64;                              \
    *(us8*)(&At[buf][base + ((un0)     ^ (ar_row & 7)) * 8]) = pk0;           \
    *(us8*)(&At[buf][base + ((un0 + 1) ^ (ar_row & 7)) * 8]) = pk1; }

  ISSUE_A(0)
  ISSUE_B(0, 0)
  WRITE_A(0)
  __syncthreads();
  int cur = 0;

  for (int j = 0; j < 4; ++j) {
    if (j < 3) { ISSUE_A((j + 1) * 64) ISSUE_B(cur ^ 1, (j + 1) * 64) }
    __builtin_amdgcn_s_setprio(1);
#pragma unroll
    for (int ds = 0; ds < 2; ++ds) {
      bf16x8 af[4], bfr[2];
#pragma unroll
      for (int m = 0; m < 4; ++m)
        af[m] = *(const bf16x8*)(&At[cur][(m * 16 + lr) * 64 + (((ds << 2) | lg) ^ (lr & 7)) * 8]);
#pragma unroll
      for (int n = 0; n < 2; ++n)
        bfr[n] = *(const bf16x8*)(&Bt[cur][(wid * 32 + n * 16 + lr) * 64 + (((ds << 2) | lg) ^ (lr & 7)) * 8]);
#pragma unroll
      for (int m = 0; m < 4; ++m)
#pragma unroll
        for (int n = 0; n < 2; ++n)
          acc[m][n] = mfma16(af[m], bfr[n], acc[m][n]);
    }
    __builtin_amdgcn_s_setprio(0);
    if (j < 3) WRITE_A(cur ^ 1)
    __syncthreads();
    cur ^= 1;
  }
#undef ISSUE_A
#undef ISSUE_B
#undef WRITE_A

#pragma unroll
  for (int n = 0; n < 2; ++n) {
    int col = n0 + wid * 32 + n * 16 + lr;
    float bb = bias[col];
    int h = col >> 6, d = col & 63;
#pragma unroll
    for (int m = 0; m < 4; ++m) {
      int rowb = m0 + m * 16 + lg * 4;
#pragma unroll
      for (int r = 0; r < 4; ++r) {
        int srow = rowb + r;
        int b = srow >> 11, s = srow & 2047;
        int bh = b * 4 + h;
        unsigned short val = f2bf(acc[m][n][r] + bb);
        if (p == 0)      Qh[(bh * 2048 + s) * 64 + d] = val;
        else if (p == 1) Kh[(bh * 2048 + s) * 64 + d] = val;
        else             VhT[((bh * 64 + d) * 2048) + s] = val;
      }
    }
  }
}

// ---- fused flash attention: pruned tile list, swapped QK^T, in-register P ----
__global__ __launch_bounds__(256) void attn(
    const unsigned short* __restrict__ Qh, const unsigned short* __restrict__ Kh,
    const unsigned short* __restrict__ VhT, const float* __restrict__ mprep,
    const int* __restrict__ proc,
    unsigned short* __restrict__ Aout) {
  __shared__ __align__(16) unsigned short Kt[2][4096];
  __shared__ __align__(16) unsigned short Vt[2][4096];
  const int bh = blockIdx.y;
  const int q0 = blockIdx.x * 64;
  const int t = threadIdx.x, lane = t & 63, wid = t >> 6;
  const int lr = lane & 15, lg = lane >> 4;
  const int qrow = q0 + wid * 16;
  const unsigned short* Kbase = Kh + bh * 131072;
  const unsigned short* Vbase = VhT + bh * 131072;
  const float* mrow = mprep + (bh >> 2) * 2048;
  const int* plist = proc + (bh >> 2) * 33;
  const int lx = lr & 7;          // swizzle xor
  const int lgh = lg >> 1, lgo = (lg & 1) * 4;

  bf16x8 qf[2];
#pragma unroll
  for (int ds = 0; ds < 2; ++ds)
    qf[ds] = *(const bf16x8*)(Qh + (bh * 2048 + qrow + lr) * 64 + ds * 32 + lg * 8);

  f32x4 accO[4] = {};           // accO[db][r] = O[q=lr][d=db*16+lg*4+r]
  float mrun = -3.0e38f, lrun = 0.f;

#define STAGE(buf, kv)                                                        \
  {                                                                           \
    _Pragma("unroll")                                                         \
    for (int i = 0; i < 2; ++i) {                                             \
      int u = t + i * 256;                                                    \
      int row = u >> 3, g = (u & 7) ^ (row & 7);                              \
      gl2lds16(Kbase + ((kv) + row) * 64 + g * 8, &Kt[buf][u * 8]);           \
      gl2lds16(Vbase + row * 2048 + (kv) + g * 8, &Vt[buf][u * 8]);           \
    }                                                                         \
  }

  const int cnt = plist[0];                 // block-uniform
  STAGE(0, plist[1] * 64)
  __syncthreads();
  int cur = 0;

  for (int j = 0; j < cnt; ++j) {
    const int kv0 = plist[1 + j] * 64;
    if (j + 1 < cnt) STAGE(cur ^ 1, plist[2 + j] * 64)

    // S^T = K Q^T : accS[kb][r] = S[q=lr][k = kv0 + kb*16 + lg*4 + r]
    f32x4 accS[4] = {};
    __builtin_amdgcn_s_setprio(1);
#pragma unroll
    for (int kb = 0; kb < 4; ++kb)
#pragma unroll
      for (int ds = 0; ds < 2; ++ds) {
        bf16x8 kf = *(const bf16x8*)(&Kt[cur][((kb * 16 + lr) << 3 | (((ds << 2) | lg) ^ lx)) * 8]);
        accS[kb] = mfma16(kf, qf[ds], accS[kb]);
      }
    __builtin_amdgcn_s_setprio(0);

    // logits in log2 domain (per-lane row q=lr)
    f32x4 sv[4];
#pragma unroll
    for (int kb = 0; kb < 4; ++kb) {
      f32x4 mk = *(const f32x4*)(mrow + kv0 + kb * 16 + lg * 4);
      sv[kb] = accS[kb] * 0.1803368801f + mk;
    }
    float mx0 = fmaxf(fmaxf(sv[0][0], sv[0][1]), fmaxf(sv[0][2], sv[0][3]));
    float mx1 = fmaxf(fmaxf(sv[1][0], sv[1][1]), fmaxf(sv[1][2], sv[1][3]));
    float mx2 = fmaxf(fmaxf(sv[2][0], sv[2][1]), fmaxf(sv[2][2], sv[2][3]));
    float mx3 = fmaxf(fmaxf(sv[3][0], sv[3][1]), fmaxf(sv[3][2], sv[3][3]));
    float mx = fmaxf(fmaxf(mx0, mx1), fmaxf(mx2, mx3));
    mx = fmaxf(mx, __shfl_xor(mx, 16));
    mx = fmaxf(mx, __shfl_xor(mx, 32));
    float mnew = fmaxf(mrun, mx);
    float al = __builtin_amdgcn_exp2f(mrun - mnew);
    mrun = mnew;

    float px[4][4];
    float lsum = 0.f;
#pragma unroll
    for (int kb = 0; kb < 4; ++kb) {
      float s = 0.f;
#pragma unroll
      for (int r = 0; r < 4; ++r) {
        px[kb][r] = __builtin_amdgcn_exp2f(sv[kb][r] - mnew);
        s += px[kb][r];
      }
      lsum += s;
    }
    lsum += __shfl_xor(lsum, 16);
    lsum += __shfl_xor(lsum, 32);
    lrun = lrun * al + lsum;
#pragma unroll
    for (int db = 0; db < 4; ++db) accO[db] *= al;

    // P fragments, fully lane-local (k-permutation matched by V reads)
    bf16x8 pf[2];
#pragma unroll
    for (int ks = 0; ks < 2; ++ks) {
      bf16x8 p;
#pragma unroll
      for (int r = 0; r < 4; ++r) {
        p[r]     = (bf16_t)px[2 * ks][r];
        p[r + 4] = (bf16_t)px[2 * ks + 1][r];
      }
      pf[ks] = p;
    }

    // O^T += V^T P^T   (A = V^T rows d, k permuted; B = pf)
    __builtin_amdgcn_s_setprio(1);
#pragma unroll
    for (int ks = 0; ks < 2; ++ks)
#pragma unroll
      for (int db = 0; db < 4; ++db) {
        int row = db * 16 + lr;
        int u0 = (row << 3) | (((ks << 2) | lgh) ^ lx);
        int u1 = (row << 3) | (((ks << 2) | 2 | lgh) ^ lx);
        bf16x4 v0 = *(const bf16x4*)(&Vt[cur][u0 * 8 + lgo]);
        bf16x4 v1 = *(const bf16x4*)(&Vt[cur][u1 * 8 + lgo]);
        bf16x8 vf = __builtin_shufflevector(v0, v1, 0, 1, 2, 3, 4, 5, 6, 7);
        accO[db] = mfma16(vf, pf[ks], accO[db]);
      }
    __builtin_amdgcn_s_setprio(0);

    __syncthreads();   // drains prefetch vmcnt + releases cur buf
    cur ^= 1;
  }
#undef STAGE

  const int b = bh >> 2, h = bh & 3;
  const float inv = __builtin_amdgcn_rcpf(lrun);
  const int q = qrow + lr;
#pragma unroll
  for (int db = 0; db < 4; ++db) {
    us4 o;
#pragma unroll
    for (int r = 0; r < 4; ++r) o[r] = f2bf(accO[db][r] * inv);
    *(us4*)(&Aout[(b * 2048 + q) * 256 + h * 64 + db * 16 + lg * 4]) = o;
  }
}

// ---- output projection: 64x128 tile, BK=64, dbuf gl2lds, f32 out ----
__global__ __launch_bounds__(256) void gemm_out(
    const unsigned short* __restrict__ Aout, const unsigned short* __restrict__ wt,
    const float* __restrict__ bo, float* __restrict__ out) {
  __shared__ __align__(16) unsigned short At[2][64 * 64];
  __shared__ __align__(16) unsigned short Bt[2][128 * 64];
  const unsigned short* WT = wt + 3 * 65536;
  const int m0 = blockIdx.x * 64, n0 = blockIdx.y * 128;
  const int t = threadIdx.x, lane = t & 63;
  const int wid = t >> 6;
  const int lr = lane & 15, lg = lane >> 4;

  f32x4 acc[4][2] = {};

#define STAGE_O(buf, k0)                                                      \
  {                                                                           \
    _Pragma("unroll") for (int i = 0; i < 2; ++i) {                           \
      int u = t + i * 256;                                                    \
      int row = u >> 3, g = (u & 7) ^ (row & 7);                              \
      gl2lds16(Aout + (m0 + row) * 256 + (k0) + g * 8, &At[buf][u * 8]);      \
    }                                                                         \
    _Pragma("unroll") for (int i = 0; i < 4; ++i) {                           \
      int u = t + i * 256;                                                    \
      int row = u >> 3, g = (u & 7) ^ (row & 7);                              \
      gl2lds16(WT + (n0 + row) * 256 + (k0) + g * 8, &Bt[buf][u * 8]);        \
    }                                                                         \
  }

  STAGE_O(0, 0)
  __syncthreads();
  int cur = 0;

  for (int j = 0; j < 4; ++j) {
    if (j < 3) STAGE_O(cur ^ 1, (j + 1) * 64)
    __builtin_amdgcn_s_setprio(1);
#pragma unroll
    for (int ds = 0; ds < 2; ++ds) {
      bf16x8 af[4], bfr[2];
#pragma unroll
      for (int m = 0; m < 4; ++m)
        af[m] = *(const bf16x8*)(&At[cur][(m * 16 + lr) * 64 + (((ds << 2) | lg) ^ (lr & 7)) * 8]);
#pragma unroll
      for (int n = 0; n < 2; ++n)
        bfr[n] = *(const bf16x8*)(&Bt[cur][(wid * 32 + n * 16 + lr) * 64 + (((ds << 2) | lg) ^ (lr & 7)) * 8]);
#pragma unroll
      for (int m = 0; m < 4; ++m)
#pragma unroll
        for (int n = 0; n < 2; ++n)
          acc[m][n] = mfma16(af[m], bfr[n], acc[m][n]);
    }
    __builtin_amdgcn_s_setprio(0);
    __syncthreads();
    cur ^= 1;
  }
#undef STAGE_O

#pragma unroll
  for (int n = 0; n < 2; ++n) {
    int col = n0 + wid * 32 + n * 16 + lr;
    float bb = bo[col];
#pragma unroll
    for (int m = 0; m < 4; ++m) {
      int rowb = m0 + m * 16 + lg * 4;
#pragma unroll
      for (int r = 0; r < 4; ++r)
        out[(rowb + r) * 256 + col] = acc[m][n][r] + bb;
    }
  }
}

extern "C" void kernel_launch(void* const* d_in, const int* in_sizes, int n_in,
                              void* d_out, int out_size, void* d_ws, size_t ws_size,
                              hipStream_t stream) {
  const float* v    = (const float*)d_in[0];
  const float* k    = (const float*)d_in[1];
  const float* q    = (const float*)d_in[2];
  const float* mask = (const float*)d_in[3];
  const float* wq   = (const float*)d_in[4];
  const float* bq   = (const float*)d_in[5];
  const float* wk   = (const float*)d_in[6];
  const float* bk   = (const float*)d_in[7];
  const float* wv   = (const float*)d_in[8];
  const float* bv   = (const float*)d_in[9];
  const float* wo   = (const float*)d_in[10];
  const float* bo   = (const float*)d_in[11];
  float* out = (float*)d_out;
  char* ws = (char*)d_ws;

  // ws: wt 524288 | mprep 65536 | proc 4096 | Qh | Kh | VhT | Aout (8 MB each)
  unsigned short* wt  = (unsigned short*)(ws);
  float*          mp  = (float*)(ws + 524288);
  int*            pr  = (int*)(ws + 589824);
  unsigned short* Qh  = (unsigned short*)(ws + 593920);
  unsigned short* Kh  = (unsigned short*)(ws + 593920 + 8388608);
  unsigned short* VhT = (unsigned short*)(ws + 593920 + 2 * 8388608);
  unsigned short* Ao  = (unsigned short*)(ws + 593920 + 3 * 8388608);

  prep_w<<<dim3(65), dim3(256), 0, stream>>>(wq, wk, wv, wo, mask, wt, mp, pr);
  gemm_qkv<<<dim3(256, 2, 3), dim3(256), 0, stream>>>(q, k, v, bq, bk, bv, wt, Qh, Kh, VhT);
  attn<<<dim3(32, 32), dim3(256), 0, stream>>>(Qh, Kh, VhT, mp, pr, Ao);
  gemm_out<<<dim3(256, 2), dim3(256), 0, stream>>>(Ao, wt, bo, out);
}